// Round 8
// baseline (250.193 us; speedup 1.0000x reference)
//
#include <hip/hip_runtime.h>

// Problem constants
#define LL    262144
#define GG    8
#define JJ    8
#define FGF   16
#define WW    31
#define PAD1  15
#define LPAD  (LL + 32)      // xw positions: pp in [0, L+32), gp = pp - 16

typedef __bf16 bf16x8 __attribute__((ext_vector_type(8)));
typedef float  f32x4  __attribute__((ext_vector_type(4)));

__device__ inline unsigned short f2bf(float f) {
    unsigned int u = __float_as_uint(f);
    u = (u + 0x7FFF + ((u >> 16) & 1)) >> 16;   // RNE
    return (unsigned short)u;
}

// ---------------------------------------------------------------------------
// Kernel A: streaming transpose  x[64][L] fp32  ->  xw[g][pp][j] bf16
// (pp = gp+16, 16-position zero pads both ends), plus P pre-swizzle ->
// pwg[g][(w*16+f)*8+j] bf16 (w=31 zeroed). Pure copy kernel: no barriers,
// all loads/stores coalesced (float4 row reads, 64B/thread xw writes).
// ---------------------------------------------------------------------------
__global__ __launch_bounds__(256)
void k_xpose(const float* __restrict__ x, const float* __restrict__ p,
             const int* __restrict__ rel, unsigned short* __restrict__ xw,
             unsigned short* __restrict__ pwg)
{
    const int t = threadIdx.x;
    const int g = blockIdx.y;
    const long gp0 = (long)blockIdx.x * 1024 + t * 4;

    const long r0 = rel[g * JJ + 0], r1 = rel[g * JJ + 1];
    const long r2 = rel[g * JJ + 2], r3 = rel[g * JJ + 3];
    const long r4 = rel[g * JJ + 4], r5 = rel[g * JJ + 5];
    const long r6 = rel[g * JJ + 6], r7 = rel[g * JJ + 7];

    float4 v0 = *(const float4*)&x[r0 * LL + gp0];
    float4 v1 = *(const float4*)&x[r1 * LL + gp0];
    float4 v2 = *(const float4*)&x[r2 * LL + gp0];
    float4 v3 = *(const float4*)&x[r3 * LL + gp0];
    float4 v4 = *(const float4*)&x[r4 * LL + gp0];
    float4 v5 = *(const float4*)&x[r5 * LL + gp0];
    float4 v6 = *(const float4*)&x[r6 * LL + gp0];
    float4 v7 = *(const float4*)&x[r7 * LL + gp0];

    const size_t base = (size_t)g * LPAD + gp0 + 16;
    #define PACKC(C, off)                                                     \
        {   uint4 pk;                                                         \
            pk.x = (unsigned)f2bf(v0.C) | ((unsigned)f2bf(v1.C) << 16);       \
            pk.y = (unsigned)f2bf(v2.C) | ((unsigned)f2bf(v3.C) << 16);       \
            pk.z = (unsigned)f2bf(v4.C) | ((unsigned)f2bf(v5.C) << 16);       \
            pk.w = (unsigned)f2bf(v6.C) | ((unsigned)f2bf(v7.C) << 16);       \
            *(uint4*)&xw[(base + (off)) * 8] = pk; }
    PACKC(x, 0) PACKC(y, 1) PACKC(z, 2) PACKC(w, 3)
    #undef PACKC

    if (blockIdx.x == 0 && t < 32) {        // zero pads: pp<16 and pp>=L+16
        size_t idx = (size_t)g * LPAD + ((t < 16) ? (size_t)t
                                                  : (size_t)LL + t);
        uint4 z = {0u, 0u, 0u, 0u};
        *(uint4*)&xw[idx * 8] = z;
    }

    if (blockIdx.x == 1) {                  // P pre-swizzle (8 KB per group)
        const float* pg = p + (long)g * FGF * JJ * WW;
        #pragma unroll
        for (int k = 0; k < 16; ++k) {
            int i = t + k * 256;            // i = (w*16 + f)*8 + j
            int w = i >> 7;
            int f = (i >> 3) & 15;
            int j = i & 7;
            float v = (w < WW) ? pg[(f * JJ + j) * WW + w] : 0.0f;
            pwg[g * 4096 + i] = f2bf(v);
        }
    }
}

// ---------------------------------------------------------------------------
// Kernel B: barrier-free, LDS-free MFMA stream. Fragments load DIRECTLY from
// xw as one coalesced dwordx4 each (LDX(pp) = 16B at xw[g][pp]); rolling
// window (frag(T,s+4)==frag(T+1,s)) halves loads. A = X-frag, B = P-frag ->
// D: col=lane&15 (filter), row=q*4+reg (position) -> f32x4 coalesced stores.
// No phases => loads pipeline deep under vmcnt; per-wave BW is not capped by
// barrier drains (rounds 0-7 lesson: every phased variant stuck at <=2.9TB/s).
// Register law: LB(256,4) -> 128-VGPR cap (est. ~112 live); >=7 w/EU spills.
// ---------------------------------------------------------------------------
__global__ __launch_bounds__(256, 4)
void k_conv(const unsigned short* __restrict__ xw,
            const unsigned short* __restrict__ pwg,
            const float* __restrict__ x, const float* __restrict__ p,
            const int* __restrict__ rel, float* __restrict__ out)
{
    const int t = threadIdx.x;
    const int g = blockIdx.y;
    const long nbase = (long)blockIdx.x * 512;

    const int lane = t & 63;
    const int wid  = t >> 6;      // wave 0..3, owns positions [wid*128, +128)
    const int col  = lane & 15;
    const int q    = lane >> 4;

    const unsigned short* xg = xw + (size_t)g * LPAD * 8;
    const unsigned short* pg = pwg + g * 4096;

    bf16x8 b[8];                  // P frags: b[s] = P[f=col, j=0..7, w=s*4+q]
    #pragma unroll
    for (int s = 0; s < 8; ++s)
        b[s] = *(const bf16x8*)&pg[((s * 4 + q) * 16 + col) * 8];

    const long pb = nbase + wid * 128 + col + q + 1;   // lane's base pp
    #define LDX(pp) (*(const bf16x8*)&xg[(pp) * 8])

    bf16x8 F0a = LDX(pb + 0), F0b = LDX(pb + 4), F0c = LDX(pb + 8), F0d = LDX(pb + 12);

    #pragma unroll
    for (int T = 0; T < 8; ++T) {
        const long o = pb + T * 16 + 16;
        bf16x8 F1a = LDX(o + 0), F1b = LDX(o + 4), F1c = LDX(o + 8), F1d = LDX(o + 12);

        f32x4 acc = {0.f, 0.f, 0.f, 0.f};
        acc = __builtin_amdgcn_mfma_f32_16x16x32_bf16(F0a, b[0], acc, 0, 0, 0);
        acc = __builtin_amdgcn_mfma_f32_16x16x32_bf16(F0b, b[1], acc, 0, 0, 0);
        acc = __builtin_amdgcn_mfma_f32_16x16x32_bf16(F0c, b[2], acc, 0, 0, 0);
        acc = __builtin_amdgcn_mfma_f32_16x16x32_bf16(F0d, b[3], acc, 0, 0, 0);
        acc = __builtin_amdgcn_mfma_f32_16x16x32_bf16(F1a, b[4], acc, 0, 0, 0);
        acc = __builtin_amdgcn_mfma_f32_16x16x32_bf16(F1b, b[5], acc, 0, 0, 0);
        acc = __builtin_amdgcn_mfma_f32_16x16x32_bf16(F1c, b[6], acc, 0, 0, 0);
        acc = __builtin_amdgcn_mfma_f32_16x16x32_bf16(F1d, b[7], acc, 0, 0, 0);

        // lane holds positions (T*16 + q*4 .. +3) of filter `col`
        const long kc0 = nbase + (long)(wid * 128 + T * 16) + q * 4;
        const size_t ro = (size_t)(g * FGF + col) * LL;
        *(f32x4*)&out[ro + kc0] = acc;

        F0a = F1a; F0b = F1b; F0c = F1c; F0d = F1d;   // roll window
    }
    #undef LDX

    // ---- edge fix. Reference TRUNCATES the window at data edges: overwrite
    // first/last 15 columns in exact fp32. Barrier (block-uniform condition)
    // orders this block's main-loop stores before the overwrite.
    if (blockIdx.x == 0 || blockIdx.x == (LL / 512 - 1)) {
        __syncthreads();
        const int f  = t >> 4;
        const int qq = t & 15;
        if (qq < PAD1) {
            const bool left = (blockIdx.x == 0);
            float a = 0.0f;
            for (int j = 0; j < JJ; ++j) {
                const float* pf = p + (((long)(g * FGF + f)) * JJ + j) * WW;
                const float* xj = x + (long)rel[g * JJ + j] * LL + (left ? 0 : LL - WW);
                #pragma unroll
                for (int w = 0; w < WW; ++w) {
                    // left:  y[qq]      = sum_{w <= qq+15} x[w]      * K[w]
                    // right: y[L-15+qq] = sum_{w >= qq+1 } x[L-31+w] * K[w]
                    bool use = left ? (w <= qq + PAD1) : (w >= qq + 1);
                    if (use) a += xj[w] * pf[w];
                }
            }
            const size_t ro = (size_t)(g * FGF + f) * LL;
            out[ro + (left ? (long)qq : (long)(LL - PAD1) + qq)] = a;
        }
    }
}

// ---------------------------------------------------------------------------
// Fallback (ws too small): round-3 fused kernel, known-good at 85 us.
// ---------------------------------------------------------------------------
#define NBF   2048
#define NTHF  512
#define XTLEN (NBF + 32)
__global__ __launch_bounds__(NTHF, 6)
void conv_fused(const float* __restrict__ x, const float* __restrict__ p,
                const int* __restrict__ rel, float* __restrict__ out)
{
    __shared__ unsigned short pw[32 * 16 * 8];
    __shared__ unsigned short xt[XTLEN * 8];

    const int t = threadIdx.x;
    const int g = blockIdx.y;
    const long nbase = (long)blockIdx.x * NBF;

    const long r0 = rel[g * JJ + 0], r1 = rel[g * JJ + 1];
    const long r2 = rel[g * JJ + 2], r3 = rel[g * JJ + 3];
    const long r4 = rel[g * JJ + 4], r5 = rel[g * JJ + 5];
    const long r6 = rel[g * JJ + 6], r7 = rel[g * JJ + 7];

    #pragma unroll
    for (int it = 0; it < (XTLEN + NTHF - 1) / NTHF; ++it) {
        int c = t + it * NTHF;
        if (c < XTLEN) {
            long gp = nbase - 16 + c;
            unsigned int w0, w1, w2, w3;
            if (gp >= 0 && gp < LL) {
                float v0 = x[r0 * LL + gp], v1 = x[r1 * LL + gp];
                float v2 = x[r2 * LL + gp], v3 = x[r3 * LL + gp];
                float v4 = x[r4 * LL + gp], v5 = x[r5 * LL + gp];
                float v6 = x[r6 * LL + gp], v7 = x[r7 * LL + gp];
                w0 = (unsigned)f2bf(v0) | ((unsigned)f2bf(v1) << 16);
                w1 = (unsigned)f2bf(v2) | ((unsigned)f2bf(v3) << 16);
                w2 = (unsigned)f2bf(v4) | ((unsigned)f2bf(v5) << 16);
                w3 = (unsigned)f2bf(v6) | ((unsigned)f2bf(v7) << 16);
            } else { w0 = w1 = w2 = w3 = 0u; }
            uint4 pk; pk.x = w0; pk.y = w1; pk.z = w2; pk.w = w3;
            *(uint4*)&xt[c * 8] = pk;
        }
    }
    {
        const float* pgq = p + (long)g * FGF * JJ * WW;
        #pragma unroll
        for (int k = 0; k < 8; ++k) {
            int i = t + k * NTHF;
            int w = i >> 7, f = (i >> 3) & 15, j = i & 7;
            float v = (w < WW) ? pgq[(f * JJ + j) * WW + w] : 0.0f;
            pw[i] = f2bf(v);
        }
    }
    __syncthreads();

    const int lane = t & 63, wid = t >> 6, col = lane & 15, q = lane >> 4;
    bf16x8 b[8];
    #pragma unroll
    for (int s = 0; s < 8; ++s)
        b[s] = *(const bf16x8*)&pw[((s * 4 + q) * 16 + col) * 8];

    const int pb = wid * 256 + col + q + 1;
    #define LDF(pos) (*(const bf16x8*)&xt[(pos) * 8])
    bf16x8 F0a = LDF(pb + 0), F0b = LDF(pb + 4), F0c = LDF(pb + 8), F0d = LDF(pb + 12);
    #pragma unroll
    for (int T = 0; T < 16; ++T) {
        const int o = pb + T * 16 + 16;
        bf16x8 F1a = LDF(o + 0), F1b = LDF(o + 4), F1c = LDF(o + 8), F1d = LDF(o + 12);
        f32x4 acc = {0.f, 0.f, 0.f, 0.f};
        acc = __builtin_amdgcn_mfma_f32_16x16x32_bf16(F0a, b[0], acc, 0, 0, 0);
        acc = __builtin_amdgcn_mfma_f32_16x16x32_bf16(F0b, b[1], acc, 0, 0, 0);
        acc = __builtin_amdgcn_mfma_f32_16x16x32_bf16(F0c, b[2], acc, 0, 0, 0);
        acc = __builtin_amdgcn_mfma_f32_16x16x32_bf16(F0d, b[3], acc, 0, 0, 0);
        acc = __builtin_amdgcn_mfma_f32_16x16x32_bf16(F1a, b[4], acc, 0, 0, 0);
        acc = __builtin_amdgcn_mfma_f32_16x16x32_bf16(F1b, b[5], acc, 0, 0, 0);
        acc = __builtin_amdgcn_mfma_f32_16x16x32_bf16(F1c, b[6], acc, 0, 0, 0);
        acc = __builtin_amdgcn_mfma_f32_16x16x32_bf16(F1d, b[7], acc, 0, 0, 0);
        const long kc0 = nbase + (long)(wid * 256 + T * 16) + q * 4;
        const size_t ro = (size_t)(g * FGF + col) * LL;
        *(f32x4*)&out[ro + kc0] = acc;
        F0a = F1a; F0b = F1b; F0c = F1c; F0d = F1d;
    }
    #undef LDF

    if (blockIdx.x == 0 || blockIdx.x == (LL / NBF - 1)) {
        __syncthreads();
        if (t < 256) {
            const int f = t >> 4, qq = t & 15;
            if (qq < PAD1) {
                const bool left = (blockIdx.x == 0);
                float a = 0.0f;
                for (int j = 0; j < JJ; ++j) {
                    const float* pf = p + (((long)(g * FGF + f)) * JJ + j) * WW;
                    const float* xj = x + (long)rel[g * JJ + j] * LL + (left ? 0 : LL - WW);
                    #pragma unroll
                    for (int w = 0; w < WW; ++w) {
                        bool use = left ? (w <= qq + PAD1) : (w >= qq + 1);
                        if (use) a += xj[w] * pf[w];
                    }
                }
                const size_t ro = (size_t)(g * FGF + f) * LL;
                out[ro + (left ? (long)qq : (long)(LL - PAD1) + qq)] = a;
            }
        }
    }
}

extern "C" void kernel_launch(void* const* d_in, const int* in_sizes, int n_in,
                              void* d_out, int out_size, void* d_ws, size_t ws_size,
                              hipStream_t stream)
{
    const float* x   = (const float*)d_in[0];
    const float* p   = (const float*)d_in[1];
    const int*   rel = (const int*)d_in[2];
    float* out = (float*)d_out;

    const size_t PWG_BYTES = (size_t)GG * 4096 * 2;          // 64 KB
    const size_t XW_BYTES  = (size_t)GG * LPAD * 8 * 2;      // 33.56 MB

    if (d_ws && ws_size >= PWG_BYTES + XW_BYTES) {
        unsigned short* pwg = (unsigned short*)d_ws;
        unsigned short* xw  = (unsigned short*)((char*)d_ws + PWG_BYTES);
        k_xpose<<<dim3(LL / 1024, GG), 256, 0, stream>>>(x, p, rel, xw, pwg);
        k_conv <<<dim3(LL / 512,  GG), 256, 0, stream>>>(xw, pwg, x, p, rel, out);
    } else {
        conv_fused<<<dim3(LL / NBF, GG), NTHF, 0, stream>>>(x, p, rel, out);
    }
}

// Round 9
// 221.154 us; speedup vs baseline: 1.1313x; 1.1313x over previous
//
#include <hip/hip_runtime.h>

// Problem constants
#define LL    262144
#define GG    8
#define JJ    8
#define FGF   16
#define WW    31
#define PAD1  15
#define NB    512            // positions per tile
#define TILES 4              // pipelined tiles per block
#define NTHR  512            // 8 waves/block
#define XTLEN (NB + 32)      // 544 staged positions per tile
#define NBX   (LL / (NB * TILES))   // 128 x-blocks per group

typedef __bf16 bf16x8 __attribute__((ext_vector_type(8)));
typedef float  f32x4  __attribute__((ext_vector_type(4)));

__device__ inline unsigned short f2bf(float f) {
    unsigned int u = __float_as_uint(f);
    u = (u + 0x7FFF + ((u >> 16) & 1)) >> 16;   // RNE
    return (unsigned short)u;
}

// Y[16,L] = P[16,256]·XW[256,L] per group (K = 31w x 8j padded to 256).
// A = X-fragment, B = P-fragment (swapped) -> D: col=lane&15 (filter),
// row=q*4+reg (position) -> f32x4 coalesced stores.
//
// Structure = R3's occupancy (8-wave blocks, ~24 waves/CU) + R7's pipeline
// (ISSUE next tile's global loads -> regs BEFORE computing current tile from
// LDS buf[cur], then PACK regs -> buf[cur^1], one barrier per tile). Global
// latency hides under MFMA+ds_read of the current tile.
//
// Laws from this session:
//  - >=7 waves/EU launch bound => forced 64-VGPR class => 400MB spill (R2,R5).
//    LB(512,6) caps at 85; spill tripwire: FETCH_SIZE >> 50 MB.
//  - transpose-in-thread staging + consecutive-lane b128 LDS writes:
//    0 bank conflicts (R3-R7 measured).
//  - d_ws is poisoned by the harness every iteration (~160us fills) - unused.
__global__ __launch_bounds__(NTHR, 6)
void conv_mfma(const float* __restrict__ x, const float* __restrict__ p,
               const int* __restrict__ rel, float* __restrict__ out)
{
    __shared__ unsigned short pw[32 * 16 * 8];     // [w][f][j] bf16, w=31 zeroed (8 KB)
    __shared__ unsigned short xt[2][XTLEN * 8];    // dbuf [pos][j] bf16 (17.4 KB)

    const int t = threadIdx.x;
    const int g = blockIdx.y;
    const long tbase = (long)blockIdx.x * (NB * TILES);

    // Relation rows (uniform -> SGPRs).
    const long r0 = rel[g * JJ + 0], r1 = rel[g * JJ + 1];
    const long r2 = rel[g * JJ + 2], r3 = rel[g * JJ + 3];
    const long r4 = rel[g * JJ + 4], r5 = rel[g * JJ + 5];
    const long r6 = rel[g * JJ + 6], r7 = rel[g * JJ + 7];

    // Per-thread staged registers for one tile: chunks c = t, and t+512 (t<32)
    float A[8], C[8];

    #define ISSUE(nb2, dst, c)                                              \
        {   long gp = (nb2) - 16 + (c);                                     \
            if (gp >= 0 && gp < LL) {                                       \
                dst[0] = x[r0 * LL + gp]; dst[1] = x[r1 * LL + gp];         \
                dst[2] = x[r2 * LL + gp]; dst[3] = x[r3 * LL + gp];         \
                dst[4] = x[r4 * LL + gp]; dst[5] = x[r5 * LL + gp];         \
                dst[6] = x[r6 * LL + gp]; dst[7] = x[r7 * LL + gp];         \
            } else {                                                        \
                dst[0]=dst[1]=dst[2]=dst[3]=dst[4]=dst[5]=dst[6]=dst[7]=0.f;\
            } }

    #define ISSUE_TILE(nb2)                                                 \
        ISSUE(nb2, A, t);                                                   \
        if (t < XTLEN - NTHR) ISSUE(nb2, C, t + NTHR);

    // Pack regs -> bf16 transposed LDS. Consecutive lanes -> consecutive
    // 16B ds_write_b128: conflict-free (measured 0 conflicts R3-R7).
    #define PACK1(buf, src, c)                                              \
        {   uint4 pk;                                                       \
            pk.x = (unsigned)f2bf(src[0]) | ((unsigned)f2bf(src[1]) << 16); \
            pk.y = (unsigned)f2bf(src[2]) | ((unsigned)f2bf(src[3]) << 16); \
            pk.z = (unsigned)f2bf(src[4]) | ((unsigned)f2bf(src[5]) << 16); \
            pk.w = (unsigned)f2bf(src[6]) | ((unsigned)f2bf(src[7]) << 16); \
            *(uint4*)&xt[buf][(c) * 8] = pk; }

    #define PACK_TILE(buf)                                                  \
        PACK1(buf, A, t);                                                   \
        if (t < XTLEN - NTHR) PACK1(buf, C, t + NTHR);

    // ---- prologue: issue tile 0 loads, stage P, load b[], write xt[0]
    ISSUE_TILE(tbase);

    {   // stage P: linear LDS writes, scattered (L2-hot) global reads
        const float* pg = p + (long)g * FGF * JJ * WW;
        #pragma unroll
        for (int k = 0; k < 8; ++k) {
            int i = t + k * NTHR;            // i = (w*16 + f)*8 + j
            int w = i >> 7;
            int f = (i >> 3) & 15;
            int j = i & 7;
            float v = (w < WW) ? pg[(f * JJ + j) * WW + w] : 0.0f;
            pw[i] = f2bf(v);
        }
    }
    __syncthreads();                         // pw visible

    const int lane = t & 63;
    const int wid  = t >> 6;      // wave 0..7, owns positions [wid*64, +64) per tile
    const int col  = lane & 15;
    const int q    = lane >> 4;

    bf16x8 b[8];                             // P frags: b[s] = P[f=col, j=*, w=s*4+q]
    #pragma unroll
    for (int s = 0; s < 8; ++s)
        b[s] = *(const bf16x8*)&pw[((s * 4 + q) * 16 + col) * 8];

    PACK_TILE(0);                            // implicit vmcnt wait on A/C
    __syncthreads();                         // xt[0] ready

    const int pb = wid * 64 + col + q + 1;   // lane's base xt position
    #define LDT(buf, pos) (*(const bf16x8*)&xt[buf][(pos) * 8])

    // ---- main pipeline
    #pragma unroll
    for (int i = 0; i < TILES; ++i) {
        const int  cur = i & 1;
        const long nb  = tbase + (long)i * NB;

        if (i + 1 < TILES) { ISSUE_TILE(nb + NB); }    // overlap w/ compute

        // compute tile i from xt[cur]; rolling window
        // frag(T,s) = LDT(cur, pb + T*16 + s*4); frag(T,s+4)==frag(T+1,s)
        bf16x8 F0a = LDT(cur, pb + 0), F0b = LDT(cur, pb + 4),
               F0c = LDT(cur, pb + 8), F0d = LDT(cur, pb + 12);
        #pragma unroll
        for (int T = 0; T < 4; ++T) {
            const int o = pb + T * 16 + 16;
            bf16x8 F1a = LDT(cur, o + 0), F1b = LDT(cur, o + 4),
                   F1c = LDT(cur, o + 8), F1d = LDT(cur, o + 12);

            f32x4 acc = {0.f, 0.f, 0.f, 0.f};
            acc = __builtin_amdgcn_mfma_f32_16x16x32_bf16(F0a, b[0], acc, 0, 0, 0);
            acc = __builtin_amdgcn_mfma_f32_16x16x32_bf16(F0b, b[1], acc, 0, 0, 0);
            acc = __builtin_amdgcn_mfma_f32_16x16x32_bf16(F0c, b[2], acc, 0, 0, 0);
            acc = __builtin_amdgcn_mfma_f32_16x16x32_bf16(F0d, b[3], acc, 0, 0, 0);
            acc = __builtin_amdgcn_mfma_f32_16x16x32_bf16(F1a, b[4], acc, 0, 0, 0);
            acc = __builtin_amdgcn_mfma_f32_16x16x32_bf16(F1b, b[5], acc, 0, 0, 0);
            acc = __builtin_amdgcn_mfma_f32_16x16x32_bf16(F1c, b[6], acc, 0, 0, 0);
            acc = __builtin_amdgcn_mfma_f32_16x16x32_bf16(F1d, b[7], acc, 0, 0, 0);

            // lane holds positions (T*16 + q*4 .. +3) of filter `col`
            const long kc0 = nb + (long)(wid * 64 + T * 16) + q * 4;
            const size_t ro = (size_t)(g * FGF + col) * LL;
            *(f32x4*)&out[ro + kc0] = acc;

            F0a = F1a; F0b = F1b; F0c = F1c; F0d = F1d;
        }

        if (i + 1 < TILES) { PACK_TILE(cur ^ 1); }     // write next buffer
        __syncthreads();   // xt[cur^1] ready; xt[cur] free for overwrite
    }
    #undef LDT

    // ---- merged edge fix. Reference TRUNCATES the window at data edges:
    // overwrite first/last 15 columns in exact fp32. The loop's final
    // __syncthreads() (vmcnt(0)-drained) orders main-loop stores before this.
    if (blockIdx.x == 0 || blockIdx.x == NBX - 1) {
        if (t < 256) {
            const int f  = t >> 4;
            const int qq = t & 15;
            if (qq < PAD1) {
                const bool left = (blockIdx.x == 0);
                float a = 0.0f;
                for (int j = 0; j < JJ; ++j) {
                    const float* pf = p + (((long)(g * FGF + f)) * JJ + j) * WW;
                    const float* xj = x + (long)rel[g * JJ + j] * LL + (left ? 0 : LL - WW);
                    #pragma unroll
                    for (int w = 0; w < WW; ++w) {
                        // left:  y[qq]      = sum_{w <= qq+15} x[w]      * K[w]
                        // right: y[L-15+qq] = sum_{w >= qq+1 } x[L-31+w] * K[w]
                        bool use = left ? (w <= qq + PAD1) : (w >= qq + 1);
                        if (use) a += xj[w] * pf[w];
                    }
                }
                const size_t ro = (size_t)(g * FGF + f) * LL;
                out[ro + (left ? (long)qq : (long)(LL - PAD1) + qq)] = a;
            }
        }
    }
}

extern "C" void kernel_launch(void* const* d_in, const int* in_sizes, int n_in,
                              void* d_out, int out_size, void* d_ws, size_t ws_size,
                              hipStream_t stream)
{
    const float* x   = (const float*)d_in[0];
    const float* p   = (const float*)d_in[1];
    const int*   rel = (const int*)d_in[2];
    float* out = (float*)d_out;

    dim3 grid(NBX, GG);   // (128, 8) = 1024 blocks
    conv_mfma<<<grid, NTHR, 0, stream>>>(x, p, rel, out);
}